// Round 2
// baseline (439.861 us; speedup 1.0000x reference)
//
#include <hip/hip_runtime.h>
#include <hip/hip_bf16.h>

typedef __bf16 bf16;
typedef __bf16 bf16x8 __attribute__((ext_vector_type(8)));
typedef float  f32x4  __attribute__((ext_vector_type(4)));

#define MDIM 4096
#define NDIM 4096
#define KDIM 4096
#define BM 128
#define BN 128
#define BK 32

__device__ __forceinline__ float softplus_eps(float r) {
    // sigma = log1p(exp(r)) + 1e-8 ; r in [-5.5,-2.5] so exp never overflows
    return log1pf(expf(r)) + 1e-8f;
}

// ---- prologue: W_bf16[o*K+i] = bf16(mu + softplus(rho)*eps), 4 elems/thread ----
__global__ void sample_weight_kernel(const float4* __restrict__ mu,
                                     const float4* __restrict__ rho,
                                     const float4* __restrict__ eps,
                                     ushort4* __restrict__ out, int n4) {
    int i = blockIdx.x * blockDim.x + threadIdx.x;
    if (i >= n4) return;
    float4 m = mu[i], r = rho[i], e = eps[i];
    float w0 = m.x + softplus_eps(r.x) * e.x;
    float w1 = m.y + softplus_eps(r.y) * e.y;
    float w2 = m.z + softplus_eps(r.z) * e.z;
    float w3 = m.w + softplus_eps(r.w) * e.w;
    ushort4 o;
    o.x = __builtin_bit_cast(unsigned short, (bf16)w0);
    o.y = __builtin_bit_cast(unsigned short, (bf16)w1);
    o.z = __builtin_bit_cast(unsigned short, (bf16)w2);
    o.w = __builtin_bit_cast(unsigned short, (bf16)w3);
    out[i] = o;
}

__global__ void cvt_x_kernel(const float4* __restrict__ x,
                             ushort4* __restrict__ out, int n4) {
    int i = blockIdx.x * blockDim.x + threadIdx.x;
    if (i >= n4) return;
    float4 v = x[i];
    ushort4 o;
    o.x = __builtin_bit_cast(unsigned short, (bf16)v.x);
    o.y = __builtin_bit_cast(unsigned short, (bf16)v.y);
    o.z = __builtin_bit_cast(unsigned short, (bf16)v.z);
    o.w = __builtin_bit_cast(unsigned short, (bf16)v.w);
    out[i] = o;
}

__global__ void sample_bias_kernel(const float* __restrict__ mu,
                                   const float* __restrict__ rho,
                                   const float* __restrict__ eps,
                                   float* __restrict__ out, int n) {
    int i = blockIdx.x * blockDim.x + threadIdx.x;
    if (i < n) out[i] = mu[i] + softplus_eps(rho[i]) * eps[i];
}

// ---- async global->LDS, 16B per lane, dest = uniform base + lane*16 ----
__device__ __forceinline__ void gload_lds16(const void* g, void* l) {
    __builtin_amdgcn_global_load_lds(
        (const __attribute__((address_space(1))) void*)g,
        (__attribute__((address_space(3))) void*)l, 16, 0, 0);
}

// ---- GEMM: C[b][o] = sum_k A[b][k]*B[o][k] + bias[o]  (both A,B row-major [*,K]) ----
// m97 structure: 128x128 tile, BK=32, 4 waves (2x2), 4x4 16x16x32-bf16 frags/wave.
__global__ __launch_bounds__(256) void gemm_bt_kernel(const bf16* __restrict__ A,
                                                      const bf16* __restrict__ B,
                                                      const float* __restrict__ bias,
                                                      float* __restrict__ C) {
    __shared__ __align__(16) bf16 As[BM * BK];   // [128][32] linear (gload_lds needs linear)
    __shared__ __align__(16) bf16 Bs[BN * BK];

    // XCD-aware swizzle: 1024 blocks, 1024%8==0 -> simple form is bijective
    const int nBN = NDIM / BN;                       // 32
    const int cpx = (MDIM / BM) * nBN / 8;           // 128
    int bid = blockIdx.x;
    int swz = (bid & 7) * cpx + (bid >> 3);
    int bm = swz / nBN;
    int bn = swz % nBN;

    const int tid  = threadIdx.x;
    const int wave = tid >> 6;
    const int lane = tid & 63;
    const int wm = wave >> 1;          // 0..1 : 64-row group
    const int wn = wave & 1;           // 0..1 : 64-col group

    // staging: tile = 128 rows x 64B = 512 x 16B chunks; thread t owns chunks t, t+256
    const int rowA = bm * BM + (tid >> 2);
    const int rowB = bn * BN + (tid >> 2);
    const int kofs = (tid & 3) * 8;                  // bf16 elems
    const bf16* gA0 = A + rowA * KDIM + kofs;
    const bf16* gA1 = gA0 + 64 * KDIM;
    const bf16* gB0 = B + rowB * KDIM + kofs;
    const bf16* gB1 = gB0 + 64 * KDIM;
    const unsigned s0 = wave * 1024;                 // LDS byte base, call 1 (rows 0..63)
    const unsigned s1 = 4096 + wave * 1024;          // call 2 (rows 64..127)

    f32x4 acc[4][4] = {};

    const int rsel = lane & 15;
    const int ksel = (lane >> 4) * 8;

    for (int kb = 0; kb < KDIM; kb += BK) {
        gload_lds16(gA0 + kb, (char*)As + s0);
        gload_lds16(gA1 + kb, (char*)As + s1);
        gload_lds16(gB0 + kb, (char*)Bs + s0);
        gload_lds16(gB1 + kb, (char*)Bs + s1);
        __syncthreads();   // drains vmcnt, tiles ready

        bf16x8 af[4], bfr[4];
        #pragma unroll
        for (int m = 0; m < 4; ++m)
            af[m] = *(const bf16x8*)&As[(wm * 64 + m * 16 + rsel) * BK + ksel];
        #pragma unroll
        for (int n = 0; n < 4; ++n)
            bfr[n] = *(const bf16x8*)&Bs[(wn * 64 + n * 16 + rsel) * BK + ksel];
        #pragma unroll
        for (int m = 0; m < 4; ++m)
            #pragma unroll
            for (int n = 0; n < 4; ++n)
                acc[m][n] = __builtin_amdgcn_mfma_f32_16x16x32_bf16(
                                af[m], bfr[n], acc[m][n], 0, 0, 0);
        __syncthreads();   // all reads done before restage
    }

    // epilogue: C/D layout col=lane&15, row=(lane>>4)*4+reg (m89-verified)
    #pragma unroll
    for (int n = 0; n < 4; ++n) {
        int gc = bn * BN + wn * 64 + n * 16 + (lane & 15);
        float bv = bias[gc];
        #pragma unroll
        for (int m = 0; m < 4; ++m) {
            int gr = bm * BM + wm * 64 + m * 16 + (lane >> 4) * 4;
            float* cp = C + gr * NDIM + gc;
            #pragma unroll
            for (int r = 0; r < 4; ++r)
                cp[r * NDIM] = acc[m][n][r] + bv;
        }
    }
}

extern "C" void kernel_launch(void* const* d_in, const int* in_sizes, int n_in,
                              void* d_out, int out_size, void* d_ws, size_t ws_size,
                              hipStream_t stream) {
    const float* x    = (const float*)d_in[0];
    const float* wmu  = (const float*)d_in[1];
    const float* wrho = (const float*)d_in[2];
    const float* bmu  = (const float*)d_in[3];
    const float* brho = (const float*)d_in[4];
    const float* weps = (const float*)d_in[5];
    const float* beps = (const float*)d_in[6];
    float* out = (float*)d_out;

    // workspace: W_bf16 (32MB) | x_bf16 (32MB) | bias_f32 (16KB)
    bf16*  w_bf = (bf16*)d_ws;
    bf16*  x_bf = (bf16*)((char*)d_ws + (size_t)NDIM * KDIM * 2);
    float* b_f  = (float*)((char*)d_ws + (size_t)NDIM * KDIM * 4);

    const int n4 = MDIM * KDIM / 4;   // 4,194,304
    sample_weight_kernel<<<n4 / 256, 256, 0, stream>>>(
        (const float4*)wmu, (const float4*)wrho, (const float4*)weps,
        (ushort4*)w_bf, n4);
    cvt_x_kernel<<<n4 / 256, 256, 0, stream>>>(
        (const float4*)x, (ushort4*)x_bf, n4);
    sample_bias_kernel<<<NDIM / 256, 256, 0, stream>>>(bmu, brho, beps, b_f, NDIM);

    gemm_bt_kernel<<<(MDIM / BM) * (NDIM / BN), 256, 0, stream>>>(x_bf, w_bf, b_f, out);
}

// Round 3
// 378.149 us; speedup vs baseline: 1.1632x; 1.1632x over previous
//
#include <hip/hip_runtime.h>
#include <hip/hip_bf16.h>

typedef __bf16 bf16;
typedef __bf16 bf16x8 __attribute__((ext_vector_type(8)));
typedef float  f32x4  __attribute__((ext_vector_type(4)));

#define MDIM 4096
#define NDIM 4096
#define KDIM 4096

__device__ __forceinline__ float softplus_eps(float r) {
    return log1pf(expf(r)) + 1e-8f;
}

// ---- prologue kernels (unchanged from round 2) ----
__global__ void sample_weight_kernel(const float4* __restrict__ mu,
                                     const float4* __restrict__ rho,
                                     const float4* __restrict__ eps,
                                     ushort4* __restrict__ out, int n4) {
    int i = blockIdx.x * blockDim.x + threadIdx.x;
    if (i >= n4) return;
    float4 m = mu[i], r = rho[i], e = eps[i];
    float w0 = m.x + softplus_eps(r.x) * e.x;
    float w1 = m.y + softplus_eps(r.y) * e.y;
    float w2 = m.z + softplus_eps(r.z) * e.z;
    float w3 = m.w + softplus_eps(r.w) * e.w;
    ushort4 o;
    o.x = __builtin_bit_cast(unsigned short, (bf16)w0);
    o.y = __builtin_bit_cast(unsigned short, (bf16)w1);
    o.z = __builtin_bit_cast(unsigned short, (bf16)w2);
    o.w = __builtin_bit_cast(unsigned short, (bf16)w3);
    out[i] = o;
}

__global__ void cvt_x_kernel(const float4* __restrict__ x,
                             ushort4* __restrict__ out, int n4) {
    int i = blockIdx.x * blockDim.x + threadIdx.x;
    if (i >= n4) return;
    float4 v = x[i];
    ushort4 o;
    o.x = __builtin_bit_cast(unsigned short, (bf16)v.x);
    o.y = __builtin_bit_cast(unsigned short, (bf16)v.y);
    o.z = __builtin_bit_cast(unsigned short, (bf16)v.z);
    o.w = __builtin_bit_cast(unsigned short, (bf16)v.w);
    out[i] = o;
}

__global__ void sample_bias_kernel(const float* __restrict__ mu,
                                   const float* __restrict__ rho,
                                   const float* __restrict__ eps,
                                   float* __restrict__ out, int n) {
    int i = blockIdx.x * blockDim.x + threadIdx.x;
    if (i < n) out[i] = mu[i] + softplus_eps(rho[i]) * eps[i];
}

// ---- async global->LDS, 16B/lane, dest = wave-uniform base + lane*16 ----
__device__ __forceinline__ void gload_lds16(const bf16* g, char* l) {
    __builtin_amdgcn_global_load_lds(
        (const __attribute__((address_space(1))) void*)g,
        (__attribute__((address_space(3))) void*)l, 16, 0, 0);
}

#define BAR()   __builtin_amdgcn_s_barrier()
#define LGKM0() asm volatile("s_waitcnt lgkmcnt(0)" ::: "memory")
#define VM6()   asm volatile("s_waitcnt vmcnt(6)" ::: "memory")
#define PRIO(p) __builtin_amdgcn_s_setprio(p)
#define mm(a, b, c) __builtin_amdgcn_mfma_f32_16x16x32_bf16((a), (b), (c), 0, 0, 0)

// ---- 256x256 8-phase GEMM (m201 structure): C[b][o] = sum_k A[b][k]B[o][k] + bias[o]
// 512 thr / 8 waves (2M x 4N), BK=64, 2 dbuf slots x (A 32KB + B 32KB) = 128KB LDS.
// LDS tile [256 rows][64 cols] bf16, 16B-chunk swizzle: chunk ^= (row&7) (T2).
// Stage schedule (1 half-tile = 2 gloads / phase), issue order per tile [B0,B1,A0,A1]:
//   p1:(T+1)A1->s1  p2:(T+2)B0->s0  p3:(T+2)B1  p4:(T+2)A0 +vmcnt(6)
//   p5:(T+2)A1      p6:(T+3)B0->s1  p7:(T+3)B1  p8:(T+3)A0 +vmcnt(6)
// Reads: B fully + A(m0-3) at p1/p5; A(m4-7) at p2/p6  -> each region's stage is
// >=1 barrier after its last read (WAR-safe); vmcnt(6)=3 halves in flight (T4).
__global__ __launch_bounds__(512, 1) void gemm8p_kernel(const bf16* __restrict__ A,
                                                        const bf16* __restrict__ B,
                                                        const float* __restrict__ bias,
                                                        float* __restrict__ C) {
    extern __shared__ __align__(16) char lds[];   // 131072 B

    const int tid  = threadIdx.x;
    const int wave = tid >> 6, lane = tid & 63;
    const int wm = wave >> 2, wn = wave & 3;       // 2M x 4N wave grid
    const int rsel = lane & 15, hi = lane >> 4;

    // XCD swizzle (256 blocks, 256%8==0 -> bijective)
    int bid = blockIdx.x;
    int swz = (bid & 7) * 32 + (bid >> 3);
    const int bm = swz >> 4, bn = swz & 15;

    // staging: thread owns row (tid>>3) of each 64-row gload segment, 16B chunk (tid&7),
    // pre-swizzled global source chunk = (tid&7) ^ (row&7)
    const int srow = tid >> 3;
    const int sch  = ((tid & 7) ^ (srow & 7)) * 8;          // bf16 elems
    const bf16* pA = A + (size_t)(bm * 256 + srow) * KDIM + sch;
    const bf16* pB = B + (size_t)(bn * 256 + srow) * KDIM + sch;
    char* ldsw = lds + wave * 1024;                          // wave-uniform

#define SLOT(s) ((s) * 65536)
#define STAGE_A(t, s, h) do { \
    gload_lds16(pA + (size_t)((h) * 128) * KDIM + (t) * 64,      ldsw + SLOT(s) + (h) * 16384); \
    gload_lds16(pA + (size_t)((h) * 128 + 64) * KDIM + (t) * 64, ldsw + SLOT(s) + (h) * 16384 + 8192); } while (0)
#define STAGE_B(t, s, h) do { \
    gload_lds16(pB + (size_t)((h) * 128) * KDIM + (t) * 64,      ldsw + SLOT(s) + 32768 + (h) * 16384); \
    gload_lds16(pB + (size_t)((h) * 128 + 64) * KDIM + (t) * 64, ldsw + SLOT(s) + 32768 + (h) * 16384 + 8192); } while (0)

    // ds_read addresses: row = (wm*128|wn*64) + frag*16 + rsel, byte = row*128 + (chunk^(row&7))*16
    const int cx  = rsel & 7;
    const int ck0 = (hi ^ cx) * 16;          // k-step 0 chunk byte
    const int ck1 = ((hi + 4) ^ cx) * 16;    // k-step 1
    const int aBase = wm * 16384 + rsel * 128;
    const int bBase = 32768 + wn * 8192 + rsel * 128;
#define LDA(s, m, k) (*(const bf16x8*)(lds + SLOT(s) + aBase + (m) * 2048 + ((k) ? ck1 : ck0)))
#define LDB(s, n, k) (*(const bf16x8*)(lds + SLOT(s) + bBase + (n) * 2048 + ((k) ? ck1 : ck0)))

    f32x4 acc[8][4] = {};
    bf16x8 rA0[4][2], rA1[4][2], rB[4][2];

    // prologue: tiles 0 (->slot0) and 1's first 3 halves (->slot1), canonical order
    STAGE_B(0, 0, 0); STAGE_B(0, 0, 1); STAGE_A(0, 0, 0); STAGE_A(0, 0, 1);
    STAGE_B(1, 1, 0); STAGE_B(1, 1, 1); STAGE_A(1, 1, 0);
    VM6();            // 14 issued, <=6 outstanding -> tile0 landed
    BAR();

    for (int i = 0; i < 32; ++i) {
        const int t1 = (2 * i + 1) & 63, t2 = (2 * i + 2) & 63, t3 = (2 * i + 3) & 63;

        // ---- phase 1 (slot0): read B[all] + A[m0-3]; MFMA m0-3 x n0-1
        #pragma unroll
        for (int n = 0; n < 4; ++n) { rB[n][0] = LDB(0, n, 0); rB[n][1] = LDB(0, n, 1); }
        #pragma unroll
        for (int m = 0; m < 4; ++m) { rA0[m][0] = LDA(0, m, 0); rA0[m][1] = LDA(0, m, 1); }
        STAGE_A(t1, 1, 1);
        BAR(); LGKM0(); PRIO(1);
        #pragma unroll
        for (int m = 0; m < 4; ++m)
            #pragma unroll
            for (int n = 0; n < 2; ++n) {
                acc[m][n] = mm(rA0[m][0], rB[n][0], acc[m][n]);
                acc[m][n] = mm(rA0[m][1], rB[n][1], acc[m][n]);
            }
        PRIO(0); BAR();

        // ---- phase 2 (slot0): read A[m4-7]; MFMA m4-7 x n0-1
        #pragma unroll
        for (int m = 0; m < 4; ++m) { rA1[m][0] = LDA(0, m + 4, 0); rA1[m][1] = LDA(0, m + 4, 1); }
        STAGE_B(t2, 0, 0);
        BAR(); LGKM0(); PRIO(1);
        #pragma unroll
        for (int m = 0; m < 4; ++m)
            #pragma unroll
            for (int n = 0; n < 2; ++n) {
                acc[m + 4][n] = mm(rA1[m][0], rB[n][0], acc[m + 4][n]);
                acc[m + 4][n] = mm(rA1[m][1], rB[n][1], acc[m + 4][n]);
            }
        PRIO(0); BAR();

        // ---- phase 3 (slot0): MFMA m4-7 x n2-3
        STAGE_B(t2, 0, 1);
        BAR(); LGKM0(); PRIO(1);
        #pragma unroll
        for (int m = 0; m < 4; ++m)
            #pragma unroll
            for (int n = 2; n < 4; ++n) {
                acc[m + 4][n] = mm(rA1[m][0], rB[n][0], acc[m + 4][n]);
                acc[m + 4][n] = mm(rA1[m][1], rB[n][1], acc[m + 4][n]);
            }
        PRIO(0); BAR();

        // ---- phase 4 (slot0): MFMA m0-3 x n2-3; vmcnt(6) -> tile T+1 landed
        STAGE_A(t2, 0, 0);
        VM6();
        BAR(); LGKM0(); PRIO(1);
        #pragma unroll
        for (int m = 0; m < 4; ++m)
            #pragma unroll
            for (int n = 2; n < 4; ++n) {
                acc[m][n] = mm(rA0[m][0], rB[n][0], acc[m][n]);
                acc[m][n] = mm(rA0[m][1], rB[n][1], acc[m][n]);
            }
        PRIO(0); BAR();

        // ---- phase 5 (slot1): read B[all] + A[m0-3]; MFMA m0-3 x n0-1
        #pragma unroll
        for (int n = 0; n < 4; ++n) { rB[n][0] = LDB(1, n, 0); rB[n][1] = LDB(1, n, 1); }
        #pragma unroll
        for (int m = 0; m < 4; ++m) { rA0[m][0] = LDA(1, m, 0); rA0[m][1] = LDA(1, m, 1); }
        STAGE_A(t2, 0, 1);
        BAR(); LGKM0(); PRIO(1);
        #pragma unroll
        for (int m = 0; m < 4; ++m)
            #pragma unroll
            for (int n = 0; n < 2; ++n) {
                acc[m][n] = mm(rA0[m][0], rB[n][0], acc[m][n]);
                acc[m][n] = mm(rA0[m][1], rB[n][1], acc[m][n]);
            }
        PRIO(0); BAR();

        // ---- phase 6 (slot1): read A[m4-7]; MFMA m4-7 x n0-1
        #pragma unroll
        for (int m = 0; m < 4; ++m) { rA1[m][0] = LDA(1, m + 4, 0); rA1[m][1] = LDA(1, m + 4, 1); }
        STAGE_B(t3, 1, 0);
        BAR(); LGKM0(); PRIO(1);
        #pragma unroll
        for (int m = 0; m < 4; ++m)
            #pragma unroll
            for (int n = 0; n < 2; ++n) {
                acc[m + 4][n] = mm(rA1[m][0], rB[n][0], acc[m + 4][n]);
                acc[m + 4][n] = mm(rA1[m][1], rB[n][1], acc[m + 4][n]);
            }
        PRIO(0); BAR();

        // ---- phase 7 (slot1): MFMA m4-7 x n2-3
        STAGE_B(t3, 1, 1);
        BAR(); LGKM0(); PRIO(1);
        #pragma unroll
        for (int m = 0; m < 4; ++m)
            #pragma unroll
            for (int n = 2; n < 4; ++n) {
                acc[m + 4][n] = mm(rA1[m][0], rB[n][0], acc[m + 4][n]);
                acc[m + 4][n] = mm(rA1[m][1], rB[n][1], acc[m + 4][n]);
            }
        PRIO(0); BAR();

        // ---- phase 8 (slot1): MFMA m0-3 x n2-3; vmcnt(6) -> tile T+2 landed
        STAGE_A(t3, 1, 0);
        VM6();
        BAR(); LGKM0(); PRIO(1);
        #pragma unroll
        for (int m = 0; m < 4; ++m)
            #pragma unroll
            for (int n = 2; n < 4; ++n) {
                acc[m][n] = mm(rA0[m][0], rB[n][0], acc[m][n]);
                acc[m][n] = mm(rA0[m][1], rB[n][1], acc[m][n]);
            }
        PRIO(0); BAR();
    }

    // ---- epilogue: C/D layout col=lane&15, row=(lane>>4)*4+reg ----
    #pragma unroll
    for (int n = 0; n < 4; ++n) {
        const int gc = bn * 256 + wn * 64 + n * 16 + rsel;
        const float bv = bias[gc];
        #pragma unroll
        for (int m = 0; m < 8; ++m) {
            const int gr = bm * 256 + wm * 128 + m * 16 + hi * 4;
            float* cp = C + (size_t)gr * NDIM + gc;
            #pragma unroll
            for (int r = 0; r < 4; ++r)
                cp[(size_t)r * NDIM] = acc[m][n][r] + bv;
        }
    }
#undef SLOT
#undef STAGE_A
#undef STAGE_B
#undef LDA
#undef LDB
}

extern "C" void kernel_launch(void* const* d_in, const int* in_sizes, int n_in,
                              void* d_out, int out_size, void* d_ws, size_t ws_size,
                              hipStream_t stream) {
    const float* x    = (const float*)d_in[0];
    const float* wmu  = (const float*)d_in[1];
    const float* wrho = (const float*)d_in[2];
    const float* bmu  = (const float*)d_in[3];
    const float* brho = (const float*)d_in[4];
    const float* weps = (const float*)d_in[5];
    const float* beps = (const float*)d_in[6];
    float* out = (float*)d_out;

    bf16*  w_bf = (bf16*)d_ws;
    bf16*  x_bf = (bf16*)((char*)d_ws + (size_t)NDIM * KDIM * 2);
    float* b_f  = (float*)((char*)d_ws + (size_t)NDIM * KDIM * 4);

    const int n4 = MDIM * KDIM / 4;
    sample_weight_kernel<<<n4 / 256, 256, 0, stream>>>(
        (const float4*)wmu, (const float4*)wrho, (const float4*)weps,
        (ushort4*)w_bf, n4);
    cvt_x_kernel<<<n4 / 256, 256, 0, stream>>>(
        (const float4*)x, (ushort4*)x_bf, n4);
    sample_bias_kernel<<<NDIM / 256, 256, 0, stream>>>(bmu, brho, beps, b_f, NDIM);

    hipFuncSetAttribute((const void*)gemm8p_kernel,
                        hipFuncAttributeMaxDynamicSharedMemorySize, 131072);
    gemm8p_kernel<<<(MDIM / 256) * (NDIM / 256), 512, 131072, stream>>>(x_bf, w_bf, b_f, out);
}